// Round 13
// baseline (368.146 us; speedup 1.0000x reference)
//
#include <hip/hip_runtime.h>
#include <math.h>

// Causal flash attention, B=2 H=16 S=2048 D=64, fp32 in/out, bf16 MFMA compute.
// R18: occupancy endgame. R16's cycle model closes as pure latency/TLP:
// time = units x serial_latency / resident_waves; grid (4 blocks/CU x 4
// waves) capped residency at 50% nominal / 29% measured while VGPR=56 allows
// 8 waves/SIMD. So: 512-thread blocks (8 waves), one (sA,63-sA) pair per
// block split into 8 chunks (8-9 units/wave), 9 LDS partial slots (39.2KB ->
// 4 blocks/CU by LDS), launch_bounds(512,8) caps VGPR at 64 (R16 inner loop
// = 56, fits). Nominal 32 waves/CU = 100%, 2x R16. Inner loop = R16 verbatim
// (R17's 2-unit ILP reverted: +12 VGPR, -2.7us). Everything else = R16:
// zero-sync two-phase loop, Q fp32 direct, prep K/V-only, coalesced frag
// buffers, in-block combine + ONE __syncthreads, final fp32 O direct.

constexpr int kS   = 2048;
constexpr int kD   = 64;
constexpr int kBH  = 32;
constexpr int kPadP = 72;           // prep-kernel LDS pad only
constexpr int kFragBH = 64 * 4 * 512;   // u16 per bh per buffer: 64 units x 4 chunks x 512

typedef short short8 __attribute__((ext_vector_type(8)));
typedef float float4v __attribute__((ext_vector_type(4)));
typedef float float16v __attribute__((ext_vector_type(16)));
typedef unsigned int u32;
typedef unsigned short u16;

static __device__ inline u16 f2bf(float f) {
  union { float f; unsigned u; } v; v.f = f;
  unsigned r = v.u + 0x7FFF + ((v.u >> 16) & 1);   // RNE
  return (u16)(r >> 16);
}

static __device__ inline short8 pack8(float4v a, float4v b) {
  short8 r;
  r[0] = (short)f2bf(a[0]); r[1] = (short)f2bf(a[1]);
  r[2] = (short)f2bf(a[2]); r[3] = (short)f2bf(a[3]);
  r[4] = (short)f2bf(b[0]); r[5] = (short)f2bf(b[1]);
  r[6] = (short)f2bf(b[2]); r[7] = (short)f2bf(b[3]);
  return r;
}

// half-swap: v_permlane32_swap_b32 A, B : A.hi-lanes <-> B.lo-lanes
static __device__ inline void swap32(u32 a, u32 b, u32& oa, u32& ob) {
#if __has_builtin(__builtin_amdgcn_permlane32_swap)
  auto r = __builtin_amdgcn_permlane32_swap(a, b, false, false);
  oa = r[0]; ob = r[1];
#else
  asm volatile("v_permlane32_swap_b32 %0, %1" : "+v"(a), "+v"(b));
  oa = a; ob = b;
#endif
}

// ---- prepass: K/V only -> fragment-order buffers ----
// Kf chunk(unit u, dk, lane): elem = K[row u*32 + (lane&31)][dk*16 + (lane>>5)*8 .. +8]
// Vf chunk(unit u, c, lane): elem = V^T[d = (c&1)*32 + (lane&31)][key u*32 + (c>>1)*16 + (lane>>5)*8 .. +8]
__global__ __launch_bounds__(256)
void prep_kernel(const float* __restrict__ K, const float* __restrict__ V,
                 u16* __restrict__ Kf, u16* __restrict__ Vf) {
  __shared__ u16 tile[64 * kPadP];
  const int tid = threadIdx.x;
  const int bh = blockIdx.y, st = blockIdx.x;
  const size_t ibase = (size_t)bh * kS * kD + (size_t)st * 64 * kD;
  const size_t fbase = (size_t)bh * kFragBH;
  const int r  = tid >> 2;        // row within 64-row tile
  const int c0 = (tid & 3) * 16;  // col start
  const int dk = tid & 3;
  const int U  = st * 2 + (r >> 5);   // global 32-row unit index
  const int lr = r & 31;
  {
    const float* kp = K + ibase + (size_t)r * kD + c0;
    float4v a = *(const float4v*)(kp);
    float4v b = *(const float4v*)(kp + 4);
    float4v c = *(const float4v*)(kp + 8);
    float4v d = *(const float4v*)(kp + 12);
    u16* dst = Kf + fbase + (size_t)(U * 4 + dk) * 512;
    *(short8*)(dst + lr * 8)        = pack8(a, b);   // h=0 chunk
    *(short8*)(dst + (32 + lr) * 8) = pack8(c, d);   // h=1 chunk
  }
  {
    const float* vp = V + ibase + (size_t)r * kD + c0;
    float4v a = *(const float4v*)(vp);
    float4v b = *(const float4v*)(vp + 4);
    float4v c = *(const float4v*)(vp + 8);
    float4v d = *(const float4v*)(vp + 12);
    u16* t = &tile[r * kPadP + c0];
    *(short8*)t       = pack8(a, b);
    *(short8*)(t + 8) = pack8(c, d);
  }
  __syncthreads();
  {
    const int dd = tid >> 2;          // d-row of V^T
    const int s0 = (tid & 3) * 16;    // key col start within tile
    short8 w0, w1;
    #pragma unroll
    for (int i = 0; i < 8; ++i) {
      w0[i] = (short)tile[(s0 + i) * kPadP + dd];
      w1[i] = (short)tile[(s0 + 8 + i) * kPadP + dd];
    }
    const int ku   = st * 2 + (s0 >> 5);        // unit index
    const int koff = s0 & 31;                   // 0 or 16
    const int c    = ((koff >> 4) << 1) | (dd >> 5);
    u16* vdst = Vf + fbase + (size_t)(ku * 4 + c) * 512;
    *(short8*)(vdst + (dd & 31) * 8)        = w0;   // h=0 (key +0..7)
    *(short8*)(vdst + (32 + (dd & 31)) * 8) = w1;   // h=1 (key +8..15)
  }
}

// ---- main flash kernel: 8-wave blocks, zero-sync two-phase loop ----
__global__ __launch_bounds__(512, 8)
void fattn_kernel(const float* __restrict__ Qp, const u16* __restrict__ Kf,
                  const u16* __restrict__ Vf, float* __restrict__ O) {
  __shared__ u32   ldsP[9][32][33];   // bf16-pair packed partials (padded)
  __shared__ float ldsL[9][32];

  const int tid  = threadIdx.x;
  const int wave = tid >> 6;          // 0..7
  const int lane = tid & 63;
  const int l31  = lane & 31;
  const int h    = lane >> 5;

  // 1024 blocks: xcd=blk&7 hosts bh {4x..4x+3}; pair index = blk>>5
  const int blk = blockIdx.x;
  const int bh  = (blk & 7) * 4 + ((blk >> 3) & 3);
  const int sA  = blk >> 5;          // 0..31 (small set)
  const int sB  = 63 - sA;           // 32..63 (large set)
  const int t   = sB + 1;            // first A-unit in concatenated range [0,65)
  const int lo  = (65 * wave) >> 3;  // 0,8,16,24,32,40,48,56
  const int hi  = (65 * (wave + 1)) >> 3;   // 8,16,24,32,40,48,56,65
  const int uT  = min(max(t, lo), hi);      // B phase: [lo,uT), A phase: [uT,hi)

  const u16* gk = Kf + (size_t)bh * kFragBH + lane * 8;   // + k*2048 + dk*512
  const u16* gv = Vf + (size_t)bh * kFragBH + lane * 8;   // + k*2048 + c*512

  float16v zf;
  #pragma unroll
  for (int i = 0; i < 16; ++i) zf[i] = 0.f;

  float16v acc0 = zf, acc1 = zf;
  float lac = 0.f;
  short8 qf[4];

  // direct fp32 Q read + scale + RNE convert
  auto loadQ = [&](int s) {
    const float scl = 0.125f * 1.44269504089f;   // 1/sqrt(64) * log2(e)
    const float* qp = Qp + ((size_t)bh * kS + (size_t)(s * 32 + l31)) * kD + h * 8;
    #pragma unroll
    for (int dk = 0; dk < 4; ++dk) {
      float4v a = *(const float4v*)(qp + dk * 16);
      float4v b = *(const float4v*)(qp + dk * 16 + 4);
      #pragma unroll
      for (int i = 0; i < 4; ++i) { a[i] *= scl; b[i] *= scl; }
      qf[dk] = pack8(a, b);
    }
  };

  auto unitCompute = [&](int k, int sdiag) {
    const u16* kp = gk + (size_t)k * 2048;
    const u16* vp = gv + (size_t)k * 2048;
    short8 kf[4], vf[4];
    #pragma unroll
    for (int i = 0; i < 4; ++i) kf[i] = *(const short8*)(kp + i * 512);
    #pragma unroll
    for (int i = 0; i < 4; ++i) vf[i] = *(const short8*)(vp + i * 512);

    // S^T = K * Q^T (rows = keys, cols = q)
    __builtin_amdgcn_s_setprio(1);
    float16v sv = __builtin_amdgcn_mfma_f32_32x32x16_bf16(kf[0], qf[0], zf, 0, 0, 0);
    sv = __builtin_amdgcn_mfma_f32_32x32x16_bf16(kf[1], qf[1], sv, 0, 0, 0);
    sv = __builtin_amdgcn_mfma_f32_32x32x16_bf16(kf[2], qf[2], sv, 0, 0, 0);
    sv = __builtin_amdgcn_mfma_f32_32x32x16_bf16(kf[3], qf[3], sv, 0, 0, 0);
    __builtin_amdgcn_s_setprio(0);

    if (k == sdiag) {   // diagonal subtile
      const int qg = sdiag * 32 + l31;
      #pragma unroll
      for (int r = 0; r < 16; ++r) {
        const int kg = k * 32 + (r & 3) + 8 * (r >> 2) + 4 * h;
        if (kg > qg) sv[r] = -1e30f;
      }
    }

    // p = exp2(s), pack (truncate) via v_perm
    u32 pk[8];
    #pragma unroll
    for (int g2 = 0; g2 < 4; ++g2) {
      const u32 u0 = __float_as_uint(__builtin_amdgcn_exp2f(sv[4 * g2 + 0]));
      const u32 u1 = __float_as_uint(__builtin_amdgcn_exp2f(sv[4 * g2 + 1]));
      const u32 u2 = __float_as_uint(__builtin_amdgcn_exp2f(sv[4 * g2 + 2]));
      const u32 u3 = __float_as_uint(__builtin_amdgcn_exp2f(sv[4 * g2 + 3]));
      pk[2 * g2]     = __builtin_amdgcn_perm(u1, u0, 0x07060302u);
      pk[2 * g2 + 1] = __builtin_amdgcn_perm(u3, u2, 0x07060302u);
    }

    // l partial: 2-accumulator sum of this lane's 16 bf16-truncated P values
    {
      float e0 = 0.f, e1 = 0.f;
      #pragma unroll
      for (int i = 0; i < 4; ++i) {
        e0 += __uint_as_float(pk[i] << 16)     + __uint_as_float(pk[i] & 0xFFFF0000u);
        e1 += __uint_as_float(pk[i + 4] << 16) + __uint_as_float(pk[i + 4] & 0xFFFF0000u);
      }
      lac += e0 + e1;
    }

    // exchange partner half via permlane32_swap; PV MFMA
    union { u32 u[4]; short8 s8; } pf;
    swap32(pk[0], pk[2], pf.u[0], pf.u[2]);
    swap32(pk[1], pk[3], pf.u[1], pf.u[3]);
    __builtin_amdgcn_s_setprio(1);
    acc0 = __builtin_amdgcn_mfma_f32_32x32x16_bf16(pf.s8, vf[0], acc0, 0, 0, 0);
    acc1 = __builtin_amdgcn_mfma_f32_32x32x16_bf16(pf.s8, vf[1], acc1, 0, 0, 0);
    __builtin_amdgcn_s_setprio(0);
    swap32(pk[4], pk[6], pf.u[0], pf.u[2]);
    swap32(pk[5], pk[7], pf.u[1], pf.u[3]);
    __builtin_amdgcn_s_setprio(1);
    acc0 = __builtin_amdgcn_mfma_f32_32x32x16_bf16(pf.s8, vf[2], acc0, 0, 0, 0);
    acc1 = __builtin_amdgcn_mfma_f32_32x32x16_bf16(pf.s8, vf[3], acc1, 0, 0, 0);
    __builtin_amdgcn_s_setprio(0);
  };

  auto dump = [&](int slot) {
    #pragma unroll
    for (int r = 0; r < 16; ++r) {
      const int row = (r & 3) + 8 * (r >> 2) + 4 * h;
      ldsP[slot][row][l31] = (u32)f2bf(acc0[r]) | ((u32)f2bf(acc1[r]) << 16);
    }
    const float lt = lac + __shfl_xor(lac, 32);
    if (lane < 32) ldsL[slot][lane] = lt;
  };

  // ---- phase B: set sB, units [lo, uT) with k = u ----
  if (lo < uT) {
    loadQ(sB);
    for (int u = lo; u < uT; ++u) unitCompute(u, sB);
    dump(wave);
    acc0 = zf; acc1 = zf; lac = 0.f;
  }
  // ---- phase A: set sA, units [uT, hi) with k = u - t ----
  if (uT < hi) {
    loadQ(sA);
    for (int u = uT; u < hi; ++u) unitCompute(u - t, sA);
    dump((lo < uT) ? 8 : wave);     // straddling wave's A partial -> slot 8
  }

  __syncthreads();

  // ---- in-block reduce: 2 sets x 32 q x 64 d; thread covers 4 packed u32 ----
  {
    const int setid = tid >> 8;          // 0 => B, 1 => A
    const int sOut  = setid ? sA : sB;
    const int q  = (tid & 255) >> 3;
    const int c0 = (tid & 7) * 4;

    // slot w (w<8) holds: B partial iff lo_w < t (phase B ran there),
    // else A partial (pure-A wave). slot 8: straddler's A partial, present
    // iff t is not a chunk boundary (boundaries in [33,64]: 40,48,56).
    float lsumv = 0.f;
    float lov[4] = {0.f, 0.f, 0.f, 0.f}, hiv[4] = {0.f, 0.f, 0.f, 0.f};
    #pragma unroll
    for (int w = 0; w < 8; ++w) {
      const int low = (65 * w) >> 3;
      const bool val = setid ? (low >= t) : (low < t);
      if (val) {
        lsumv += ldsL[w][q];
        #pragma unroll
        for (int i = 0; i < 4; ++i) {
          const u32 p = ldsP[w][q][c0 + i];
          lov[i] += __uint_as_float(p << 16);
          hiv[i] += __uint_as_float(p & 0xFFFF0000u);
        }
      }
    }
    if (setid && (t != 40) && (t != 48) && (t != 56)) {
      lsumv += ldsL[8][q];
      #pragma unroll
      for (int i = 0; i < 4; ++i) {
        const u32 p = ldsP[8][q][c0 + i];
        lov[i] += __uint_as_float(p << 16);
        hiv[i] += __uint_as_float(p & 0xFFFF0000u);
      }
    }
    const float inv = 1.f / lsumv;
    float* op = O + ((size_t)bh * kS + sOut * 32 + q) * kD;
    #pragma unroll
    for (int i = 0; i < 4; ++i) {
      op[c0 + i]      = lov[i] * inv;
      op[c0 + i + 32] = hiv[i] * inv;
    }
  }
}

extern "C" void kernel_launch(void* const* d_in, const int* in_sizes, int n_in,
                              void* d_out, int out_size, void* d_ws, size_t ws_size,
                              hipStream_t stream) {
  const float* Q = (const float*)d_in[0];
  const float* K = (const float*)d_in[1];
  const float* V = (const float*)d_in[2];
  float* O = (float*)d_out;

  const size_t nKV = (size_t)kBH * kS * kD;      // 4.19M elems
  u16* Kf = (u16*)d_ws;                          // 8.39 MB
  u16* Vf = Kf + nKV;                            // 8.39 MB

  dim3 gprep(kS / 64, kBH);
  prep_kernel<<<gprep, 256, 0, stream>>>(K, V, Kf, Vf);
  fattn_kernel<<<1024, 512, 0, stream>>>(Q, Kf, Vf, O);
}

// Round 14
// 240.972 us; speedup vs baseline: 1.5278x; 1.5278x over previous
//
#include <hip/hip_runtime.h>
#include <math.h>

// Causal flash attention, B=2 H=16 S=2048 D=64, fp32 in/out, bf16 MFMA compute.
// R19: R18 spill-fix (the pre-committed trim retry). (512,8)'s 64-VGPR cap
// spilled (VGPR=32, FETCH 541MB scratch, 285us). Relax to (512,6): cap ~84
// >= measured 56-68 demand -> no spill; 3 blocks/CU x 8 waves = 24 waves/CU
// nominal (75%), 1.5x R16's grid-capped 16. Structure unchanged from R18:
// 1024 blocks x 512 thr, one (sA,63-sA) pair split 8 ways (8-9 units/wave),
// 9 LDS partial slots (39.4KB), in-block combine + ONE __syncthreads.
// Inner loop = R16 verbatim. Q fp32 direct, prep K/V-only, coalesced frag
// buffers, zero-sync two-phase loop, final fp32 O direct.

constexpr int kS   = 2048;
constexpr int kD   = 64;
constexpr int kBH  = 32;
constexpr int kPadP = 72;           // prep-kernel LDS pad only
constexpr int kFragBH = 64 * 4 * 512;   // u16 per bh per buffer: 64 units x 4 chunks x 512

typedef short short8 __attribute__((ext_vector_type(8)));
typedef float float4v __attribute__((ext_vector_type(4)));
typedef float float16v __attribute__((ext_vector_type(16)));
typedef unsigned int u32;
typedef unsigned short u16;

static __device__ inline u16 f2bf(float f) {
  union { float f; unsigned u; } v; v.f = f;
  unsigned r = v.u + 0x7FFF + ((v.u >> 16) & 1);   // RNE
  return (u16)(r >> 16);
}

static __device__ inline short8 pack8(float4v a, float4v b) {
  short8 r;
  r[0] = (short)f2bf(a[0]); r[1] = (short)f2bf(a[1]);
  r[2] = (short)f2bf(a[2]); r[3] = (short)f2bf(a[3]);
  r[4] = (short)f2bf(b[0]); r[5] = (short)f2bf(b[1]);
  r[6] = (short)f2bf(b[2]); r[7] = (short)f2bf(b[3]);
  return r;
}

// half-swap: v_permlane32_swap_b32 A, B : A.hi-lanes <-> B.lo-lanes
static __device__ inline void swap32(u32 a, u32 b, u32& oa, u32& ob) {
#if __has_builtin(__builtin_amdgcn_permlane32_swap)
  auto r = __builtin_amdgcn_permlane32_swap(a, b, false, false);
  oa = r[0]; ob = r[1];
#else
  asm volatile("v_permlane32_swap_b32 %0, %1" : "+v"(a), "+v"(b));
  oa = a; ob = b;
#endif
}

// ---- prepass: K/V only -> fragment-order buffers ----
// Kf chunk(unit u, dk, lane): elem = K[row u*32 + (lane&31)][dk*16 + (lane>>5)*8 .. +8]
// Vf chunk(unit u, c, lane): elem = V^T[d = (c&1)*32 + (lane&31)][key u*32 + (c>>1)*16 + (lane>>5)*8 .. +8]
__global__ __launch_bounds__(256)
void prep_kernel(const float* __restrict__ K, const float* __restrict__ V,
                 u16* __restrict__ Kf, u16* __restrict__ Vf) {
  __shared__ u16 tile[64 * kPadP];
  const int tid = threadIdx.x;
  const int bh = blockIdx.y, st = blockIdx.x;
  const size_t ibase = (size_t)bh * kS * kD + (size_t)st * 64 * kD;
  const size_t fbase = (size_t)bh * kFragBH;
  const int r  = tid >> 2;        // row within 64-row tile
  const int c0 = (tid & 3) * 16;  // col start
  const int dk = tid & 3;
  const int U  = st * 2 + (r >> 5);   // global 32-row unit index
  const int lr = r & 31;
  {
    const float* kp = K + ibase + (size_t)r * kD + c0;
    float4v a = *(const float4v*)(kp);
    float4v b = *(const float4v*)(kp + 4);
    float4v c = *(const float4v*)(kp + 8);
    float4v d = *(const float4v*)(kp + 12);
    u16* dst = Kf + fbase + (size_t)(U * 4 + dk) * 512;
    *(short8*)(dst + lr * 8)        = pack8(a, b);   // h=0 chunk
    *(short8*)(dst + (32 + lr) * 8) = pack8(c, d);   // h=1 chunk
  }
  {
    const float* vp = V + ibase + (size_t)r * kD + c0;
    float4v a = *(const float4v*)(vp);
    float4v b = *(const float4v*)(vp + 4);
    float4v c = *(const float4v*)(vp + 8);
    float4v d = *(const float4v*)(vp + 12);
    u16* t = &tile[r * kPadP + c0];
    *(short8*)t       = pack8(a, b);
    *(short8*)(t + 8) = pack8(c, d);
  }
  __syncthreads();
  {
    const int dd = tid >> 2;          // d-row of V^T
    const int s0 = (tid & 3) * 16;    // key col start within tile
    short8 w0, w1;
    #pragma unroll
    for (int i = 0; i < 8; ++i) {
      w0[i] = (short)tile[(s0 + i) * kPadP + dd];
      w1[i] = (short)tile[(s0 + 8 + i) * kPadP + dd];
    }
    const int ku   = st * 2 + (s0 >> 5);        // unit index
    const int koff = s0 & 31;                   // 0 or 16
    const int c    = ((koff >> 4) << 1) | (dd >> 5);
    u16* vdst = Vf + fbase + (size_t)(ku * 4 + c) * 512;
    *(short8*)(vdst + (dd & 31) * 8)        = w0;   // h=0 (key +0..7)
    *(short8*)(vdst + (32 + (dd & 31)) * 8) = w1;   // h=1 (key +8..15)
  }
}

// ---- main flash kernel: 8-wave blocks, zero-sync two-phase loop ----
__global__ __launch_bounds__(512, 6)
void fattn_kernel(const float* __restrict__ Qp, const u16* __restrict__ Kf,
                  const u16* __restrict__ Vf, float* __restrict__ O) {
  __shared__ u32   ldsP[9][32][33];   // bf16-pair packed partials (padded)
  __shared__ float ldsL[9][32];

  const int tid  = threadIdx.x;
  const int wave = tid >> 6;          // 0..7
  const int lane = tid & 63;
  const int l31  = lane & 31;
  const int h    = lane >> 5;

  // 1024 blocks: xcd=blk&7 hosts bh {4x..4x+3}; pair index = blk>>5
  const int blk = blockIdx.x;
  const int bh  = (blk & 7) * 4 + ((blk >> 3) & 3);
  const int sA  = blk >> 5;          // 0..31 (small set)
  const int sB  = 63 - sA;           // 32..63 (large set)
  const int t   = sB + 1;            // first A-unit in concatenated range [0,65)
  const int lo  = (65 * wave) >> 3;  // 0,8,16,24,32,40,48,56
  const int hi  = (65 * (wave + 1)) >> 3;   // 8,16,24,32,40,48,56,65
  const int uT  = min(max(t, lo), hi);      // B phase: [lo,uT), A phase: [uT,hi)

  const u16* gk = Kf + (size_t)bh * kFragBH + lane * 8;   // + k*2048 + dk*512
  const u16* gv = Vf + (size_t)bh * kFragBH + lane * 8;   // + k*2048 + c*512

  float16v zf;
  #pragma unroll
  for (int i = 0; i < 16; ++i) zf[i] = 0.f;

  float16v acc0 = zf, acc1 = zf;
  float lac = 0.f;
  short8 qf[4];

  // direct fp32 Q read + scale + RNE convert
  auto loadQ = [&](int s) {
    const float scl = 0.125f * 1.44269504089f;   // 1/sqrt(64) * log2(e)
    const float* qp = Qp + ((size_t)bh * kS + (size_t)(s * 32 + l31)) * kD + h * 8;
    #pragma unroll
    for (int dk = 0; dk < 4; ++dk) {
      float4v a = *(const float4v*)(qp + dk * 16);
      float4v b = *(const float4v*)(qp + dk * 16 + 4);
      #pragma unroll
      for (int i = 0; i < 4; ++i) { a[i] *= scl; b[i] *= scl; }
      qf[dk] = pack8(a, b);
    }
  };

  auto unitCompute = [&](int k, int sdiag) {
    const u16* kp = gk + (size_t)k * 2048;
    const u16* vp = gv + (size_t)k * 2048;
    short8 kf[4], vf[4];
    #pragma unroll
    for (int i = 0; i < 4; ++i) kf[i] = *(const short8*)(kp + i * 512);
    #pragma unroll
    for (int i = 0; i < 4; ++i) vf[i] = *(const short8*)(vp + i * 512);

    // S^T = K * Q^T (rows = keys, cols = q)
    __builtin_amdgcn_s_setprio(1);
    float16v sv = __builtin_amdgcn_mfma_f32_32x32x16_bf16(kf[0], qf[0], zf, 0, 0, 0);
    sv = __builtin_amdgcn_mfma_f32_32x32x16_bf16(kf[1], qf[1], sv, 0, 0, 0);
    sv = __builtin_amdgcn_mfma_f32_32x32x16_bf16(kf[2], qf[2], sv, 0, 0, 0);
    sv = __builtin_amdgcn_mfma_f32_32x32x16_bf16(kf[3], qf[3], sv, 0, 0, 0);
    __builtin_amdgcn_s_setprio(0);

    if (k == sdiag) {   // diagonal subtile
      const int qg = sdiag * 32 + l31;
      #pragma unroll
      for (int r = 0; r < 16; ++r) {
        const int kg = k * 32 + (r & 3) + 8 * (r >> 2) + 4 * h;
        if (kg > qg) sv[r] = -1e30f;
      }
    }

    // p = exp2(s), pack (truncate) via v_perm
    u32 pk[8];
    #pragma unroll
    for (int g2 = 0; g2 < 4; ++g2) {
      const u32 u0 = __float_as_uint(__builtin_amdgcn_exp2f(sv[4 * g2 + 0]));
      const u32 u1 = __float_as_uint(__builtin_amdgcn_exp2f(sv[4 * g2 + 1]));
      const u32 u2 = __float_as_uint(__builtin_amdgcn_exp2f(sv[4 * g2 + 2]));
      const u32 u3 = __float_as_uint(__builtin_amdgcn_exp2f(sv[4 * g2 + 3]));
      pk[2 * g2]     = __builtin_amdgcn_perm(u1, u0, 0x07060302u);
      pk[2 * g2 + 1] = __builtin_amdgcn_perm(u3, u2, 0x07060302u);
    }

    // l partial: 2-accumulator sum of this lane's 16 bf16-truncated P values
    {
      float e0 = 0.f, e1 = 0.f;
      #pragma unroll
      for (int i = 0; i < 4; ++i) {
        e0 += __uint_as_float(pk[i] << 16)     + __uint_as_float(pk[i] & 0xFFFF0000u);
        e1 += __uint_as_float(pk[i + 4] << 16) + __uint_as_float(pk[i + 4] & 0xFFFF0000u);
      }
      lac += e0 + e1;
    }

    // exchange partner half via permlane32_swap; PV MFMA
    union { u32 u[4]; short8 s8; } pf;
    swap32(pk[0], pk[2], pf.u[0], pf.u[2]);
    swap32(pk[1], pk[3], pf.u[1], pf.u[3]);
    __builtin_amdgcn_s_setprio(1);
    acc0 = __builtin_amdgcn_mfma_f32_32x32x16_bf16(pf.s8, vf[0], acc0, 0, 0, 0);
    acc1 = __builtin_amdgcn_mfma_f32_32x32x16_bf16(pf.s8, vf[1], acc1, 0, 0, 0);
    __builtin_amdgcn_s_setprio(0);
    swap32(pk[4], pk[6], pf.u[0], pf.u[2]);
    swap32(pk[5], pk[7], pf.u[1], pf.u[3]);
    __builtin_amdgcn_s_setprio(1);
    acc0 = __builtin_amdgcn_mfma_f32_32x32x16_bf16(pf.s8, vf[2], acc0, 0, 0, 0);
    acc1 = __builtin_amdgcn_mfma_f32_32x32x16_bf16(pf.s8, vf[3], acc1, 0, 0, 0);
    __builtin_amdgcn_s_setprio(0);
  };

  auto dump = [&](int slot) {
    #pragma unroll
    for (int r = 0; r < 16; ++r) {
      const int row = (r & 3) + 8 * (r >> 2) + 4 * h;
      ldsP[slot][row][l31] = (u32)f2bf(acc0[r]) | ((u32)f2bf(acc1[r]) << 16);
    }
    const float lt = lac + __shfl_xor(lac, 32);
    if (lane < 32) ldsL[slot][lane] = lt;
  };

  // ---- phase B: set sB, units [lo, uT) with k = u ----
  if (lo < uT) {
    loadQ(sB);
    for (int u = lo; u < uT; ++u) unitCompute(u, sB);
    dump(wave);
    acc0 = zf; acc1 = zf; lac = 0.f;
  }
  // ---- phase A: set sA, units [uT, hi) with k = u - t ----
  if (uT < hi) {
    loadQ(sA);
    for (int u = uT; u < hi; ++u) unitCompute(u - t, sA);
    dump((lo < uT) ? 8 : wave);     // straddling wave's A partial -> slot 8
  }

  __syncthreads();

  // ---- in-block reduce: 2 sets x 32 q x 64 d; thread covers 4 packed u32 ----
  {
    const int setid = tid >> 8;          // 0 => B, 1 => A
    const int sOut  = setid ? sA : sB;
    const int q  = (tid & 255) >> 3;
    const int c0 = (tid & 7) * 4;

    // slot w (w<8) holds: B partial iff lo_w < t (phase B ran there),
    // else A partial (pure-A wave). slot 8: straddler's A partial, present
    // iff t is not a chunk boundary (boundaries in [33,64]: 40,48,56).
    float lsumv = 0.f;
    float lov[4] = {0.f, 0.f, 0.f, 0.f}, hiv[4] = {0.f, 0.f, 0.f, 0.f};
    #pragma unroll
    for (int w = 0; w < 8; ++w) {
      const int low = (65 * w) >> 3;
      const bool val = setid ? (low >= t) : (low < t);
      if (val) {
        lsumv += ldsL[w][q];
        #pragma unroll
        for (int i = 0; i < 4; ++i) {
          const u32 p = ldsP[w][q][c0 + i];
          lov[i] += __uint_as_float(p << 16);
          hiv[i] += __uint_as_float(p & 0xFFFF0000u);
        }
      }
    }
    if (setid && (t != 40) && (t != 48) && (t != 56)) {
      lsumv += ldsL[8][q];
      #pragma unroll
      for (int i = 0; i < 4; ++i) {
        const u32 p = ldsP[8][q][c0 + i];
        lov[i] += __uint_as_float(p << 16);
        hiv[i] += __uint_as_float(p & 0xFFFF0000u);
      }
    }
    const float inv = 1.f / lsumv;
    float* op = O + ((size_t)bh * kS + sOut * 32 + q) * kD;
    #pragma unroll
    for (int i = 0; i < 4; ++i) {
      op[c0 + i]      = lov[i] * inv;
      op[c0 + i + 32] = hiv[i] * inv;
    }
  }
}

extern "C" void kernel_launch(void* const* d_in, const int* in_sizes, int n_in,
                              void* d_out, int out_size, void* d_ws, size_t ws_size,
                              hipStream_t stream) {
  const float* Q = (const float*)d_in[0];
  const float* K = (const float*)d_in[1];
  const float* V = (const float*)d_in[2];
  float* O = (float*)d_out;

  const size_t nKV = (size_t)kBH * kS * kD;      // 4.19M elems
  u16* Kf = (u16*)d_ws;                          // 8.39 MB
  u16* Vf = Kf + nKV;                            // 8.39 MB

  dim3 gprep(kS / 64, kBH);
  prep_kernel<<<gprep, 256, 0, stream>>>(K, V, Kf, Vf);
  fattn_kernel<<<1024, 512, 0, stream>>>(Q, Kf, Vf, O);
}